// Round 4
// baseline (423.637 us; speedup 1.0000x reference)
//
#include <hip/hip_runtime.h>

// Problem constants (fixed by setup_inputs)
#define DIM 512
#define NQ 64
#define BATCH 2048
#define MB_ROWS 64       // batch rows per A tile
#define APAD 520         // LDS row stride (bf16 elems); 1040 B, 16B-aligned

typedef __bf16  bf16x8   __attribute__((ext_vector_type(8)));
typedef float   floatx16 __attribute__((ext_vector_type(16)));

static __device__ inline unsigned short f2bf(float f) {
    unsigned int u = __float_as_uint(f);
    return (unsigned short)((u + 0x7fffu + ((u >> 16) & 1u)) >> 16);  // RNE
}
static __device__ inline float bf2f(unsigned short h) {
    return __uint_as_float((unsigned int)h << 16);
}
static __device__ inline unsigned int pack2(float a, float b) {
    return (unsigned)f2bf(a) | ((unsigned)f2bf(b) << 16);
}

__global__ void hsq_zero_kernel(float* p) { p[threadIdx.x] = 0.0f; }

// Pack points fp32 (2048,512) -> bf16 Pb (2 MB, stays L2-resident for the GEMM)
__global__ void hsq_pack_kernel(const float* __restrict__ pts,
                                unsigned short* __restrict__ Pb) {
    const int i8 = blockIdx.x * 256 + threadIdx.x;   // 131072 groups of 8 floats
    const float4 v1 = *(const float4*)(pts + (size_t)i8 * 8);
    const float4 v2 = *(const float4*)(pts + (size_t)i8 * 8 + 4);
    uint4 wv;
    wv.x = pack2(v1.x, v1.y); wv.y = pack2(v1.z, v1.w);
    wv.z = pack2(v2.x, v2.y); wv.w = pack2(v2.z, v2.w);
    *(uint4*)(Pb + (size_t)i8 * 8) = wv;
}

// Expand q_coefs (n_mono, 64) -> W[k][e][d] (bf16, d contiguous), fused norm2.
// Read phase: lane = k so every qc load is one fully-consumed 256B row.
// Write phase: LDS transpose so 16 consecutive threads write one contiguous
// 256B chunk of a k-row.
__global__ __launch_bounds__(256, 4)
void hsq_expand_kernel(const float* __restrict__ qc,
                       unsigned short* __restrict__ W,
                       float* __restrict__ norm2) {
    const int e    = blockIdx.x;          // 0..511
    const int dblk = blockIdx.y;          // 0..3
    const int wid  = threadIdx.x >> 6;
    const int k    = threadIdx.x & 63;    // lane = quadric index
    const int d0   = dblk * 128 + wid * 32;

    __shared__ unsigned short tv[64 * 136];
    __shared__ float part[4][64];

    float v[32];
#pragma unroll
    for (int s = 0; s < 32; ++s) {
        const int d = d0 + s;
        const int i = d < e ? d : e;
        const int j = d < e ? e : d;
        const int idx = i * DIM - ((i * (i - 1)) >> 1) + (j - i);
        v[s] = qc[(size_t)idx * NQ + k];
    }

    float nacc = 0.0f;
#pragma unroll
    for (int s = 0; s < 32; ++s)
        if (d0 + s >= e) nacc += v[s] * v[s];

#pragma unroll
    for (int t = 0; t < 4; ++t) {
        float sc[8];
#pragma unroll
        for (int q = 0; q < 8; ++q) {
            const int d = d0 + t * 8 + q;
            sc[q] = v[t * 8 + q] * ((d == e) ? 2.0f : 1.41421356237309515f);
        }
        uint4 w;
        w.x = pack2(sc[0], sc[1]); w.y = pack2(sc[2], sc[3]);
        w.z = pack2(sc[4], sc[5]); w.w = pack2(sc[6], sc[7]);
        *(uint4*)&tv[k * 136 + wid * 32 + t * 8] = w;
    }
    part[wid][k] = nacc;
    __syncthreads();

#pragma unroll
    for (int r = 0; r < 4; ++r) {
        const int kk = r * 16 + (threadIdx.x >> 4);
        const int u  = threadIdx.x & 15;
        const uint4 w = *(const uint4*)&tv[kk * 136 + u * 8];
        *(uint4*)(W + ((size_t)(kk * DIM + e)) * DIM + dblk * 128 + u * 8) = w;
    }
    if (threadIdx.x < 64) {
        const float s = part[0][k] + part[1][k] + part[2][k] + part[3][k];
        atomicAdd(&norm2[k], s);
    }
}

// GEMM with W stationary in registers. Block = (k, 128-e range); 4 waves, each
// wave owns a 32-e strip and holds its 32 B-frags (128 VGPRs) for the whole
// kernel. Loops over 32 batch tiles; A staged via global_load_lds double-buffer.
// Writes per-(row,k) partial (pv, pg) for its e-range; final kernel combines.
__global__ __launch_bounds__(256, 1)
void hsq_gemm_kernel(const unsigned short* __restrict__ Pb,
                     const unsigned short* __restrict__ W,
                     const float* __restrict__ l_coefs,
                     float* __restrict__ part) {
    const int k  = blockIdx.x >> 2;      // 0..63
    const int eb = blockIdx.x & 3;       // 0..3
    const int tid  = threadIdx.x;
    const int w    = tid >> 6;
    const int lane = tid & 63;
    const int n    = lane & 31;          // MFMA row/col within 32
    const int h    = lane >> 5;          // k-half selector
    const int e0   = eb * 128 + w * 32;  // this wave's e strip base

    __shared__ unsigned short As[2][MB_ROWS * APAD];  // 2 x 66560 B
    __shared__ float red[4][MB_ROWS][2];

    // ---- Load persistent B fragments: W[k][e0+n][ks*16 + h*8 .. +8] ----
    bf16x8 Bf[32];
    {
        const unsigned short* Wb = W + (size_t)k * DIM * DIM + (size_t)(e0 + n) * DIM + h * 8;
#pragma unroll
        for (int ks = 0; ks < 32; ++ks)
            Bf[ks] = *(const bf16x8*)(Wb + ks * 16);
    }
    const float lv = l_coefs[(e0 + n) * NQ + k];

    // stage macro: 16 global_load_lds dwordx4 per wave = 16 rows of 1024 B
#define STAGE(buf_, mb_) do { \
    const unsigned short* gp_ = Pb + ((size_t)(mb_) * MB_ROWS) * DIM; \
    _Pragma("unroll") \
    for (int r16 = 0; r16 < 16; ++r16) { \
        const int row_ = w * 16 + r16; \
        __builtin_amdgcn_global_load_lds( \
            (const __attribute__((address_space(1))) unsigned int*)(gp_ + (size_t)row_ * DIM + lane * 8), \
            (__attribute__((address_space(3))) unsigned int*)&As[buf_][row_ * APAD], \
            16, 0, 0); \
    } \
} while (0)

    STAGE(0, 0);
    __syncthreads();

    for (int mb = 0; mb < 32; ++mb) {
        const int buf = mb & 1;
        if (mb < 31) STAGE(buf ^ 1, mb + 1);

        const unsigned short* Ab = As[buf];
        floatx16 acc0, acc1;
#pragma unroll
        for (int r = 0; r < 16; ++r) { acc0[r] = 0.f; acc1[r] = 0.f; }

#pragma unroll
        for (int ks = 0; ks < 32; ++ks) {
            const bf16x8 a0 = *(const bf16x8*)&Ab[(size_t)n * APAD + ks * 16 + h * 8];
            const bf16x8 a1 = *(const bf16x8*)&Ab[(size_t)(n + 32) * APAD + ks * 16 + h * 8];
            acc0 = __builtin_amdgcn_mfma_f32_32x32x16_bf16(a0, Bf[ks], acc0, 0, 0, 0);
            acc1 = __builtin_amdgcn_mfma_f32_32x32x16_bf16(a1, Bf[ks], acc1, 0, 0, 0);
        }

        // ---- Epilogue: pv = sum_e p*(0.5g+l), pg = sum_e (g+l)^2 over 32 e ----
#pragma unroll
        for (int rt = 0; rt < 2; ++rt) {
            const floatx16 a = rt ? acc1 : acc0;
#pragma unroll
            for (int r = 0; r < 16; ++r) {
                const int row = rt * 32 + (r & 3) + 8 * (r >> 2) + 4 * h;
                const float g = a[r];
                const float p = bf2f(Ab[(size_t)row * APAD + e0 + n]);
                float pvr = p * (0.5f * g + lv);
                const float gq = g + lv;
                float pgr = gq * gq;
#pragma unroll
                for (int off = 1; off < 32; off <<= 1) {
                    pvr += __shfl_xor(pvr, off);
                    pgr += __shfl_xor(pgr, off);
                }
                if (n == 0) { red[w][row][0] = pvr; red[w][row][1] = pgr; }
            }
        }
        __syncthreads();
        if (tid < MB_ROWS) {
            const float pvs = red[0][tid][0] + red[1][tid][0] + red[2][tid][0] + red[3][tid][0];
            const float pgs = red[0][tid][1] + red[1][tid][1] + red[2][tid][1] + red[3][tid][1];
            const size_t o = (((size_t)eb * BATCH + (size_t)mb * MB_ROWS + tid) * NQ + k) * 2;
            part[o] = pvs; part[o + 1] = pgs;
        }
        __syncthreads();
    }
#undef STAGE
}

// Combine 4 e-range partials into scores.
__global__ void hsq_final_kernel(const float* __restrict__ part,
                                 const float* __restrict__ norm2,
                                 const float* __restrict__ free_coefs,
                                 float* __restrict__ out) {
    const int idx = blockIdx.x * 256 + threadIdx.x;   // 0..131071
    const int k = idx & 63;
    float pv = 0.f, pg = 0.f;
#pragma unroll
    for (int eb = 0; eb < 4; ++eb) {
        const size_t o = (((size_t)eb * BATCH * NQ) + idx) * 2;
        pv += part[o]; pg += part[o + 1];
    }
    const float vals = fabsf(pv + free_coefs[k]);
    const float nrm  = sqrtf(norm2[k]);
    out[idx] = (sqrtf(0.25f * pg + vals * nrm) - 0.5f * sqrtf(pg)) / nrm;
}

extern "C" void kernel_launch(void* const* d_in, const int* in_sizes, int n_in,
                              void* d_out, int out_size, void* d_ws, size_t ws_size,
                              hipStream_t stream) {
    const float* points     = (const float*)d_in[0];  // (2048, 512)
    const float* q_coefs    = (const float*)d_in[1];  // (131328, 64)
    const float* l_coefs    = (const float*)d_in[2];  // (512, 64)
    const float* free_coefs = (const float*)d_in[3];  // (1, 64)
    float* out = (float*)d_out;                       // (2048, 64)

    char* ws = (char*)d_ws;
    unsigned short* W  = (unsigned short*)ws;                         // 32 MiB
    unsigned short* Pb = (unsigned short*)(ws + (size_t)NQ * DIM * DIM * 2);        // 2 MiB
    float* part  = (float*)(ws + (size_t)NQ * DIM * DIM * 2 + (size_t)BATCH * DIM * 2);  // 4 MiB
    float* norm2 = (float*)((char*)part + (size_t)4 * BATCH * NQ * 2 * 4);

    hsq_zero_kernel<<<1, 64, 0, stream>>>(norm2);
    hsq_pack_kernel<<<dim3(BATCH * DIM / 8 / 256), 256, 0, stream>>>(points, Pb);
    hsq_expand_kernel<<<dim3(DIM, 4), 256, 0, stream>>>(q_coefs, W, norm2);
    hsq_gemm_kernel<<<dim3(NQ * 4), 256, 0, stream>>>(Pb, W, l_coefs, part);
    hsq_final_kernel<<<dim3(BATCH * NQ / 256), 256, 0, stream>>>(part, norm2, free_coefs, out);
}

// Round 5
// 218.972 us; speedup vs baseline: 1.9347x; 1.9347x over previous
//
#include <hip/hip_runtime.h>

// Problem constants (fixed by setup_inputs)
#define DIM 512
#define NQ 64
#define BATCH 2048

typedef __bf16  bf16x8  __attribute__((ext_vector_type(8)));
typedef float   floatx4 __attribute__((ext_vector_type(4)));

static __device__ inline unsigned short f2bf(float f) {
    unsigned int u = __float_as_uint(f);
    return (unsigned short)((u + 0x7fffu + ((u >> 16) & 1u)) >> 16);  // RNE
}
static __device__ inline float bf2f(unsigned short h) {
    return __uint_as_float((unsigned int)h << 16);
}
static __device__ inline unsigned int pack2(float a, float b) {
    return (unsigned)f2bf(a) | ((unsigned)f2bf(b) << 16);
}

// Pack points fp32 (2048,512) -> bf16 Pb (2 MB, L2-resident for the GEMM)
__global__ void hsq_pack_kernel(const float* __restrict__ pts,
                                unsigned short* __restrict__ Pb) {
    const int i8 = blockIdx.x * 256 + threadIdx.x;
    const float4 v1 = *(const float4*)(pts + (size_t)i8 * 8);
    const float4 v2 = *(const float4*)(pts + (size_t)i8 * 8 + 4);
    uint4 wv;
    wv.x = pack2(v1.x, v1.y); wv.y = pack2(v1.z, v1.w);
    wv.z = pack2(v2.x, v2.y); wv.w = pack2(v2.z, v2.w);
    *(uint4*)(Pb + (size_t)i8 * 8) = wv;
}

// Expand q_coefs (n_mono,64) -> W[k][e][d] (bf16, d contiguous). norm2 partials
// go to npart[k][block] as PLAIN stores (the old 64-lane atomicAdd serialized
// ~65K RMWs per cache line — that was the hidden ~110 us).
__global__ __launch_bounds__(256, 4)
void hsq_expand_kernel(const float* __restrict__ qc,
                       unsigned short* __restrict__ W,
                       float* __restrict__ npart) {
    const int e    = blockIdx.x;          // 0..511
    const int dblk = blockIdx.y;          // 0..3
    const int pb   = blockIdx.y * 512 + blockIdx.x;   // 0..2047
    const int wid  = threadIdx.x >> 6;
    const int k    = threadIdx.x & 63;    // lane = quadric index
    const int d0   = dblk * 128 + wid * 32;

    __shared__ unsigned short tv[64 * 136];
    __shared__ float part[4][64];

    float v[32];
#pragma unroll
    for (int s = 0; s < 32; ++s) {
        const int d = d0 + s;
        const int i = d < e ? d : e;
        const int j = d < e ? e : d;
        const int idx = i * DIM - ((i * (i - 1)) >> 1) + (j - i);
        v[s] = qc[(size_t)idx * NQ + k];
    }

    float nacc = 0.0f;
#pragma unroll
    for (int s = 0; s < 32; ++s)
        if (d0 + s >= e) nacc += v[s] * v[s];

#pragma unroll
    for (int t = 0; t < 4; ++t) {
        float sc[8];
#pragma unroll
        for (int q = 0; q < 8; ++q) {
            const int d = d0 + t * 8 + q;
            sc[q] = v[t * 8 + q] * ((d == e) ? 2.0f : 1.41421356237309515f);
        }
        uint4 w;
        w.x = pack2(sc[0], sc[1]); w.y = pack2(sc[2], sc[3]);
        w.z = pack2(sc[4], sc[5]); w.w = pack2(sc[6], sc[7]);
        *(uint4*)&tv[k * 136 + wid * 32 + t * 8] = w;
    }
    part[wid][k] = nacc;
    __syncthreads();

#pragma unroll
    for (int r = 0; r < 4; ++r) {
        const int kk = r * 16 + (threadIdx.x >> 4);
        const int u  = threadIdx.x & 15;
        const uint4 w = *(const uint4*)&tv[kk * 136 + u * 8];
        *(uint4*)(W + ((size_t)(kk * DIM + e)) * DIM + dblk * 128 + u * 8) = w;
    }
    if (threadIdx.x < 64) {
        npart[(size_t)k * 2048 + pb] =
            part[0][k] + part[1][k] + part[2][k] + part[3][k];
    }
}

// Reduce npart[k][0..2047] -> norm2[k]. 8 blocks x 256 threads, coalesced.
__global__ void hsq_normred_kernel(const float* __restrict__ npart,
                                   float* __restrict__ norm2) {
    const int t = threadIdx.x;
    const int k = blockIdx.x * 8 + (t >> 5);
    const int q = t & 31;
    const float4* src = (const float4*)(npart + (size_t)k * 2048 + q * 64);
    float s = 0.f;
#pragma unroll
    for (int i = 0; i < 16; ++i) {
        const float4 v = src[i];
        s += v.x + v.y + v.z + v.w;
    }
#pragma unroll
    for (int off = 1; off < 32; off <<= 1) s += __shfl_xor(s, off);
    if (q == 0) norm2[k] = s;
}

// m97-style GEMM: 128(m) x 128(n = 128 e's of one k) tiles, BK=64, both A and
// B double-buffered in LDS via global_load_lds(16B), XOR-swizzled layout so
// ds_read_b128 is bank-floor. 4 waves, each computes a 64x64 quadrant via 4x4
// mfma_16x16x32. Epilogue: p harvested from the live A-tile at the matching
// K-iter; per-(row,k,eb) partials (pv,pg) written coalesced; final combines.
__global__ __launch_bounds__(256, 2)
void hsq_gemm_kernel(const unsigned short* __restrict__ Pb,
                     const unsigned short* __restrict__ W,
                     const float* __restrict__ l_coefs,
                     float2* __restrict__ part) {
    // XCD swizzle: each XCD owns 8 k's; concurrent set = one k slab (512 KB).
    const int bid = blockIdx.x;
    const int xcd = bid & 7;
    const int loc = bid >> 3;                 // 0..511
    const int k   = xcd * 8 + (loc >> 6);     // 0..63
    const int rem = loc & 63;
    const int eb  = rem >> 4;                 // 0..3 (e-range of 128)
    const int m0  = (rem & 15) * 128;         // batch-tile base

    const int tid   = threadIdx.x;
    const int w     = tid >> 6;
    const int lane  = tid & 63;
    const int mhalf = w >> 1, nhalf = w & 1;
    const int c     = lane & 15;              // MFMA col
    const int quad  = lane >> 4;              // MFMA k-chunk / D row-block

    __shared__ unsigned short Ab[2][128 * 64];   // 2 x 16 KB
    __shared__ unsigned short Bb[2][128 * 64];   // 2 x 16 KB
    __shared__ float red[2][128][2];

    const unsigned short* Wk = W + (size_t)k * DIM * DIM + (size_t)eb * 128 * DIM;

    // stage one BK=64 slab of A and B; LDS slot = chunk ^ (row&7) (bank swizzle)
#define STAGE(buf_, it_) do {                                                   \
    const int rl_ = (lane >> 3);                                                \
    const int s_  = lane & 7;                                                   \
    _Pragma("unroll")                                                           \
    for (int i_ = 0; i_ < 4; ++i_) {                                            \
        const int row_ = w * 32 + i_ * 8 + rl_;                                 \
        const int gch_ = s_ ^ (row_ & 7);                                       \
        __builtin_amdgcn_global_load_lds(                                       \
            (const __attribute__((address_space(1))) unsigned int*)             \
                (Pb + (size_t)(m0 + row_) * DIM + (it_) * 64 + gch_ * 8),       \
            (__attribute__((address_space(3))) unsigned int*)                   \
                &Ab[buf_][(w * 32 + i_ * 8) * 64], 16, 0, 0);                   \
        __builtin_amdgcn_global_load_lds(                                       \
            (const __attribute__((address_space(1))) unsigned int*)             \
                (Wk + (size_t)row_ * DIM + (it_) * 64 + gch_ * 8),              \
            (__attribute__((address_space(3))) unsigned int*)                   \
                &Bb[buf_][(w * 32 + i_ * 8) * 64], 16, 0, 0);                   \
    }                                                                           \
} while (0)

    floatx4 acc[4][4];
#pragma unroll
    for (int mt = 0; mt < 4; ++mt)
#pragma unroll
        for (int nt = 0; nt < 4; ++nt)
            acc[mt][nt] = (floatx4){0.f, 0.f, 0.f, 0.f};

    float lcv[4];
#pragma unroll
    for (int nt = 0; nt < 4; ++nt)
        lcv[nt] = l_coefs[(eb * 128 + nhalf * 64 + nt * 16 + c) * NQ + k];

    float pf[4][4][4];   // [mt][r][nt] — p values for epilogue (harvested)
    const int hit = 2 * eb + nhalf;    // K-iter whose A-slab covers this wave's e's

    STAGE(0, 0);
    __syncthreads();

    for (int it = 0; it < 8; ++it) {
        const int buf = it & 1;
        if (it < 7) STAGE(buf ^ 1, it + 1);

        if (it == hit) {   // harvest p[row][e] from live A-tile (d-window == e-window)
#pragma unroll
            for (int mt = 0; mt < 4; ++mt)
#pragma unroll
                for (int r = 0; r < 4; ++r) {
                    const int row = mhalf * 64 + mt * 16 + quad * 4 + r;
#pragma unroll
                    for (int nt = 0; nt < 4; ++nt) {
                        const int slot = (nt * 2 + (c >> 3)) ^ (row & 7);
                        pf[mt][r][nt] = bf2f(Ab[buf][row * 64 + slot * 8 + (c & 7)]);
                    }
                }
        }

#pragma unroll
        for (int ks = 0; ks < 2; ++ks) {
            bf16x8 af[4], bfr[4];
#pragma unroll
            for (int mt = 0; mt < 4; ++mt) {
                const int row = mhalf * 64 + mt * 16 + c;
                const int slot = (ks * 4 + quad) ^ (row & 7);
                af[mt] = *(const bf16x8*)&Ab[buf][row * 64 + slot * 8];
            }
#pragma unroll
            for (int nt = 0; nt < 4; ++nt) {
                const int er = nhalf * 64 + nt * 16 + c;
                const int slot = (ks * 4 + quad) ^ (er & 7);
                bfr[nt] = *(const bf16x8*)&Bb[buf][er * 64 + slot * 8];
            }
#pragma unroll
            for (int mt = 0; mt < 4; ++mt)
#pragma unroll
                for (int nt = 0; nt < 4; ++nt)
                    acc[mt][nt] = __builtin_amdgcn_mfma_f32_16x16x32_bf16(
                        af[mt], bfr[nt], acc[mt][nt], 0, 0, 0);
        }
        __syncthreads();
    }
#undef STAGE

    // ---- Epilogue: pv = sum_e p*(0.5g+l), pg = sum_e (g+l)^2 (this eb's 128 e) ----
#pragma unroll
    for (int mt = 0; mt < 4; ++mt)
#pragma unroll
        for (int r = 0; r < 4; ++r) {
            float pv = 0.f, pg = 0.f;
#pragma unroll
            for (int nt = 0; nt < 4; ++nt) {
                const float g = acc[mt][nt][r];
                const float l = lcv[nt];
                pv += pf[mt][r][nt] * (0.5f * g + l);
                const float gq = g + l;
                pg += gq * gq;
            }
#pragma unroll
            for (int off = 1; off < 16; off <<= 1) {
                pv += __shfl_xor(pv, off);
                pg += __shfl_xor(pg, off);
            }
            if (c == 0) {
                const int row = mhalf * 64 + mt * 16 + quad * 4 + r;
                red[nhalf][row][0] = pv;
                red[nhalf][row][1] = pg;
            }
        }
    __syncthreads();

    if (tid < 128) {
        const float pv = red[0][tid][0] + red[1][tid][0];
        const float pg = red[0][tid][1] + red[1][tid][1];
        part[((size_t)(eb * NQ + k)) * BATCH + m0 + tid] = make_float2(pv, pg);
    }
}

// Combine 4 e-range partials into scores. Block per k: coalesced part reads.
__global__ void hsq_final_kernel(const float2* __restrict__ part,
                                 const float* __restrict__ norm2,
                                 const float* __restrict__ free_coefs,
                                 float* __restrict__ out) {
    const int k = blockIdx.x;
    const float nrm = sqrtf(norm2[k]);
    const float fc  = free_coefs[k];
#pragma unroll
    for (int i = 0; i < 8; ++i) {
        const int b = i * 256 + threadIdx.x;
        float pv = 0.f, pg = 0.f;
#pragma unroll
        for (int eb = 0; eb < 4; ++eb) {
            const float2 t = part[((size_t)(eb * NQ + k)) * BATCH + b];
            pv += t.x; pg += t.y;
        }
        const float vals = fabsf(pv + fc);
        out[(size_t)b * NQ + k] = (sqrtf(0.25f * pg + vals * nrm) - 0.5f * sqrtf(pg)) / nrm;
    }
}

extern "C" void kernel_launch(void* const* d_in, const int* in_sizes, int n_in,
                              void* d_out, int out_size, void* d_ws, size_t ws_size,
                              hipStream_t stream) {
    const float* points     = (const float*)d_in[0];  // (2048, 512)
    const float* q_coefs    = (const float*)d_in[1];  // (131328, 64)
    const float* l_coefs    = (const float*)d_in[2];  // (512, 64)
    const float* free_coefs = (const float*)d_in[3];  // (1, 64)
    float* out = (float*)d_out;                       // (2048, 64)

    char* ws = (char*)d_ws;
    unsigned short* W  = (unsigned short*)ws;                              // 32 MiB
    unsigned short* Pb = (unsigned short*)(ws + 33554432);                 // 2 MiB
    float2*         part  = (float2*)(ws + 35651584);                      // 4 MiB
    float*          npart = (float*)(ws + 39845888);                       // 512 KiB
    float*          norm2 = (float*)(ws + 40370176);                       // 256 B

    hsq_pack_kernel<<<dim3(BATCH * DIM / 8 / 256), 256, 0, stream>>>(points, Pb);
    hsq_expand_kernel<<<dim3(DIM, 4), 256, 0, stream>>>(q_coefs, W, npart);
    hsq_normred_kernel<<<dim3(8), 256, 0, stream>>>(npart, norm2);
    hsq_gemm_kernel<<<dim3(NQ * 64), 256, 0, stream>>>(Pb, W, l_coefs, part);
    hsq_final_kernel<<<dim3(NQ), 256, 0, stream>>>(part, norm2, free_coefs, out);
}